// Round 15
// baseline (35.917 us; speedup 1.0000x reference)
//
#include <hip/hip_runtime.h>
#include <hip/hip_bf16.h>

// Problem constants (from setup_inputs): bs=16, nq=64, ngt=32, D=4096, ncls=33
#define BS   16
#define NQ   64
#define NGT  32
#define DIM  4096
#define NCLS 33

#define QT      4               // heat rows per block (2048 blocks -> ~8/CU)
#define NCHUNK  8               // D split
#define CHUNK   (DIM / NCHUNK)  // 512

typedef float vfloat4 __attribute__((ext_vector_type(4)));

// ---------------------------------------------------------------------------
// Kernel 1: partial cost  Cp[b][q][g][c] = sum_{d in chunk c} |heat[b,q,d]-gt[b,g,d]|
// (byte-identical to round 14, passing)
// ---------------------------------------------------------------------------
__global__ __launch_bounds__(256) void cost_kernel(
    const float* __restrict__ heat, const float* __restrict__ gt,
    float* __restrict__ Cp)
{
    __shared__ float hrow[QT][CHUNK];   // 8 KB
    const int bid  = blockIdx.x;        // 2048 blocks
    const int b    = bid & 15;
    const int rest = bid >> 4;          // 0..127
    const int qt   = rest & (NQ / QT - 1);  // 0..15
    const int c    = rest >> 4;         // 0..7
    const int q0   = qt * QT;

    const float* hbase = heat + ((size_t)(b * NQ + q0)) * DIM + c * CHUNK;
    #pragma unroll
    for (int i = threadIdx.x; i < QT * CHUNK / 4; i += 256) {
        int r = i >> 7;        // / (CHUNK/4 = 128)
        int k = i & 127;
        const vfloat4* src = (const vfloat4*)(hbase + (size_t)r * DIM) + k;
        ((vfloat4*)hrow[r])[k] = __builtin_nontemporal_load(src);
    }
    __syncthreads();

    const int wave = threadIdx.x >> 6;
    const int lane = threadIdx.x & 63;
    const int g0 = wave * 8;
    const float* gbase = gt + ((size_t)(b * NGT + g0)) * DIM + c * CHUNK;

    float acc[8][QT];
    #pragma unroll
    for (int g = 0; g < 8; ++g)
        #pragma unroll
        for (int q = 0; q < QT; ++q) acc[g][q] = 0.f;

    #pragma unroll
    for (int i0 = 0; i0 < CHUNK / 4; i0 += 64) {   // 2 iterations
        const int i = i0 + lane;
        float4 hv[QT];
        #pragma unroll
        for (int q = 0; q < QT; ++q) hv[q] = ((float4*)hrow[q])[i];
        #pragma unroll
        for (int g = 0; g < 8; ++g) {
            float4 gv = ((const float4*)(gbase + (size_t)g * DIM))[i];
            #pragma unroll
            for (int q = 0; q < QT; ++q) {
                acc[g][q] += fabsf(hv[q].x - gv.x) + fabsf(hv[q].y - gv.y) +
                             fabsf(hv[q].z - gv.z) + fabsf(hv[q].w - gv.w);
            }
        }
    }

    float r[32];
    #pragma unroll
    for (int k = 0; k < 32; ++k) r[k] = acc[k >> 2][k & 3];
    #pragma unroll
    for (int n = 32, m = 1; n > 1; n >>= 1, m <<= 1) {
        #pragma unroll
        for (int k = 0; k < 32; ++k) {
            if (k < n / 2) {
                float a  = r[2 * k], bb = r[2 * k + 1];
                bool  hi = (lane & m) != 0;
                float keep = hi ? bb : a;
                float send = hi ? a : bb;
                r[k] = keep + __shfl_xor(send, m);
            }
        }
    }
    float tot = r[0] + __shfl_xor(r[0], 32);
    if (lane < 32) {
        int gl = lane >> 2, ql = lane & 3;
        Cp[(((size_t)(b * NQ + (q0 + ql))) * NGT + (g0 + gl)) * NCHUNK + c] = tot;
    }
}

// ---------------------------------------------------------------------------
// Helpers.
// ---------------------------------------------------------------------------
template<int CTRL>
__device__ __forceinline__ float dppmin_t(float x) {
    int t = __builtin_amdgcn_update_dpp(__float_as_int(x), __float_as_int(x),
                                        CTRL, 0xf, 0xf, false);
    return fminf(x, __int_as_float(t));
}
__device__ __forceinline__ float rdlane_f(float x, int l) {
    return __int_as_float(__builtin_amdgcn_readlane(__float_as_int(x), l));
}
// Exact min over all 64 lanes, wave-uniform result.
__device__ __forceinline__ float wavemin64(float x) {
    x = dppmin_t<0xB1>(x);    // quad_perm xor1
    x = dppmin_t<0x4E>(x);    // quad_perm xor2
    x = dppmin_t<0x141>(x);   // row_half_mirror -> min over 8
    x = dppmin_t<0x140>(x);   // row_mirror      -> min over 16
    x = dppmin_t<0x142>(x);   // row_bcast15
    x = dppmin_t<0x143>(x);   // row_bcast31 -> lane63 = min over 64
    return rdlane_f(x, 63);
}

// 32 NAMED float registers (no array -> no address-taking -> no scratch
// demotion, rule #20) + macro-expanded 31-cndmask binary select tree.
// The uniform index is forced into a VGPR so the conditions are per-lane
// v_cmp -> v_cndmask (no scalar branch / jump table, round-6 failure mode).
// Returns exactly cost[i][lane] -> solver trajectory bit-identical.
#define RPT32(M) M(0) M(1) M(2) M(3) M(4) M(5) M(6) M(7) M(8) M(9) M(10) M(11) \
    M(12) M(13) M(14) M(15) M(16) M(17) M(18) M(19) M(20) M(21) M(22) M(23) \
    M(24) M(25) M(26) M(27) M(28) M(29) M(30) M(31)
#define DECLC(n) float c##n;
#define LOADC(n) c##n = cost[(n << 6) + lane];

#define SELTREE(dst, isrc) do {                                               \
    int vi_; asm("v_mov_b32 %0, %1" : "=v"(vi_) : "s"(isrc));                 \
    const bool m0 = (vi_ & 1), m1 = (vi_ & 2), m2 = (vi_ & 4),                \
               m3 = (vi_ & 8), m4 = (vi_ & 16);                               \
    float a0 = m0 ? c1 : c0,   a1 = m0 ? c3 : c2,   a2 = m0 ? c5 : c4,        \
          a3 = m0 ? c7 : c6,   a4 = m0 ? c9 : c8,   a5 = m0 ? c11 : c10,      \
          a6 = m0 ? c13 : c12, a7 = m0 ? c15 : c14, a8 = m0 ? c17 : c16,      \
          a9 = m0 ? c19 : c18, a10 = m0 ? c21 : c20, a11 = m0 ? c23 : c22,    \
          a12 = m0 ? c25 : c24, a13 = m0 ? c27 : c26, a14 = m0 ? c29 : c28,   \
          a15 = m0 ? c31 : c30;                                               \
    float bb0 = m1 ? a1 : a0,  bb1 = m1 ? a3 : a2,  bb2 = m1 ? a5 : a4,       \
          bb3 = m1 ? a7 : a6,  bb4 = m1 ? a9 : a8,  bb5 = m1 ? a11 : a10,     \
          bb6 = m1 ? a13 : a12, bb7 = m1 ? a15 : a14;                         \
    float d0 = m2 ? bb1 : bb0, d1 = m2 ? bb3 : bb2,                           \
          d2 = m2 ? bb5 : bb4, d3 = m2 ? bb7 : bb6;                           \
    float e0 = m3 ? d1 : d0,   e1 = m3 ? d3 : d2;                             \
    dst = m4 ? e1 : e0;                                                       \
} while (0)

// ---------------------------------------------------------------------------
// Kernel 2: exact rectangular LSAP (Jonker-Volgenant + greedy P1 row init).
// Identical to round 10/14 (passing) EXCEPT the Dijkstra inner loop reads
// cost[i][lane] from 32 named VGPRs via SELTREE instead of a ~120-cy ds_read.
// P2/P3 dual tightening remain BANNED (rounds 11/12 failed with them).
// ---------------------------------------------------------------------------
__global__ __launch_bounds__(256, 1) void lsap_kernel(
    const float* __restrict__ Cp, const float* __restrict__ prob,
    const int* __restrict__ label, int* __restrict__ out)
{
    __shared__ float cost[NGT * NQ];
    const int b = blockIdx.x;
    const int tid = threadIdx.x;

    for (int idx = tid; idx < NQ * NGT; idx += 256) {
        int q = idx & 63;
        int g = idx >> 6;
        const float* p = &Cp[(((size_t)(b * NQ + q)) * NGT + g) * NCHUNK];
        float4 v4a = *(const float4*)p;
        float4 v4b = *(const float4*)(p + 4);
        int lb = label[b * NGT + g];
        float cpr = 1.0f - prob[((size_t)(b * NQ + q)) * NCLS + lb];
        float s = ((v4a.x + v4a.y) + (v4a.z + v4a.w)) +
                  ((v4b.x + v4b.y) + (v4b.z + v4b.w));
        cost[g * 64 + q] = s + cpr;
    }
    __syncthreads();
    if (tid >= 64) return;            // wave 0 solves alone
    const int lane = tid;

    // This lane's column of the cost matrix -> 32 NAMED registers (once).
    RPT32(DECLC)
    RPT32(LOADC)

    const float INF = __builtin_inff();
    float v = 0.f;        // dual for column `lane`
    float u_reg = 0.f;    // dual for row `lane` (valid lane<32)
    int c4r = -1;         // col4row for row `lane` (valid lane<32)
    int r4c = -1;         // row4col for column `lane`

    // ---- P1: greedy row reduction + matching, groups of 8 (as round 14) ----
    #pragma unroll
    for (int gb = 0; gb < NGT; gb += 8) {
        float xs[8]; float ms[8]; int js[8];
        #pragma unroll
        for (int t = 0; t < 8; ++t) xs[t] = cost[((gb + t) << 6) + lane];
        #pragma unroll
        for (int t = 0; t < 8; ++t) {
            ms[t] = wavemin64(xs[t]);
            unsigned long long ball = __ballot(xs[t] == ms[t]);
            js[t] = __ffsll(ball) - 1;
        }
        #pragma unroll
        for (int t = 0; t < 8; ++t) {
            int g = gb + t, j = js[t];
            int rtaken = __builtin_amdgcn_readlane(r4c, j);
            if (rtaken < 0) {
                if (lane == j) r4c = g;
                if (lane == g) c4r = j;
            }
            if (lane == g) u_reg = ms[t];
        }
    }

    // ---- Dijkstra for the unmatched rows ----
    for (int cur = 0; cur < NGT; ++cur) {
        if (__builtin_amdgcn_readlane(c4r, cur) >= 0) continue;  // greedy-matched

        unsigned SRmask = 0;
        float shortest = INF;
        int pathv = 0;
        bool SC = false;
        float minVal = 0.f;
        int i = cur;
        int sink = -1;

        while (sink < 0) {
            SRmask |= (1u << i);
            float ci; SELTREE(ci, i);           // register select, no LDS latency
            float ui = rdlane_f(u_reg, i);
            float lowest = minVal + ci - ui - v;
            if (!SC && lowest < shortest) { shortest = lowest; pathv = i; }
            float masked = SC ? INF : shortest;
            float mv = wavemin64(masked);
            unsigned long long ball = __ballot(masked == mv);
            int j = __ffsll(ball) - 1;          // first-index tie-break
            minVal = mv;
            if (lane == j) SC = true;
            int rr = __builtin_amdgcn_readlane(r4c, j);
            if (rr < 0) sink = j;
            else        i = rr;
        }

        // ---- dual updates (pre-augment col4row) ----
        if (lane == cur) u_reg += minVal;
        {
            float shc = __shfl(shortest, c4r & 63);
            bool rowupd = (lane < NGT) && (lane != cur) && ((SRmask >> lane) & 1u);
            if (rowupd) u_reg += minVal - shc;
        }
        if (SC) v -= minVal - shortest;

        // ---- augment back from sink ----
        int j = sink;
        while (true) {
            int ii = __builtin_amdgcn_readlane(pathv, j);
            if (lane == j) r4c = ii;
            int prev = __builtin_amdgcn_readlane(c4r, ii);
            if (lane == ii) c4r = j;
            if (ii == cur) break;
            j = prev;
        }
    }

    // ---- argsort(col4row) and write (rows, cols) ----
    int cc = c4r;
    int rank = 0;
    for (int t = 0; t < NGT; ++t) {
        int ct = __shfl(c4r, t);
        rank += (ct < cc) ? 1 : 0;
    }
    if (lane < NGT) {
        out[b * NGT + rank] = cc;                   // rows: matched query idx
        out[BS * NGT + b * NGT + rank] = lane;      // cols: corresponding gt idx
    }
}

extern "C" void kernel_launch(void* const* d_in, const int* in_sizes, int n_in,
                              void* d_out, int out_size, void* d_ws, size_t ws_size,
                              hipStream_t stream) {
    const float* prob  = (const float*)d_in[0];
    const int*   label = (const int*)d_in[1];
    const float* heat  = (const float*)d_in[2];
    const float* gt    = (const float*)d_in[3];
    int* out = (int*)d_out;
    float* Cp = (float*)d_ws;   // BS*NQ*NGT*NCHUNK floats = 1 MiB

    cost_kernel<<<dim3(BS * (NQ / QT) * NCHUNK), dim3(256), 0, stream>>>(heat, gt, Cp);
    lsap_kernel<<<dim3(BS), dim3(256), 0, stream>>>(Cp, prob, label, out);
}

// Round 16
// 33.835 us; speedup vs baseline: 1.0615x; 1.0615x over previous
//
#include <hip/hip_runtime.h>
#include <hip/hip_bf16.h>

// Problem constants (from setup_inputs): bs=16, nq=64, ngt=32, D=4096, ncls=33
#define BS   16
#define NQ   64
#define NGT  32
#define DIM  4096
#define NCLS 33

#define QT      4               // heat rows per block (2048 blocks -> ~8/CU)
#define NCHUNK  8               // D split
#define CHUNK   (DIM / NCHUNK)  // 512

// ---------------------------------------------------------------------------
// FINAL (round-10 revert): best measured configuration, 33.83 us.
//   C  ~ 9-10 us : latency-floor at 8 blocks/CU (QT=8->4 was the last win;
//                  nontemporal staging r14 = neutral)
//   L  ~ 16-17 us: serial exact JV; greedy P1 init = -4 us (r8); P2/P3 dual
//                  tightening BANNED (r11/r12 absmax=15 — restructures the
//                  Dijkstra trajectory); register-select replacements for the
//                  ds_read failed 3x (r6 +5us, r9 2x, r15 +2us)
//   ov ~ 4-5 us : two graph dispatches + true dependency
// ---------------------------------------------------------------------------

// ---------------------------------------------------------------------------
// Kernel 1: partial cost  Cp[b][q][g][c] = sum_{d in chunk c} |heat[b,q,d]-gt[b,g,d]|
// Block = (b, q-tile of 4, chunk): 2048 blocks; b = bid&15 pins batches to XCDs.
// 4 waves x (8 gt x 4 q) register tile; 8 KB LDS heat staging.
// ---------------------------------------------------------------------------
__global__ __launch_bounds__(256) void cost_kernel(
    const float* __restrict__ heat, const float* __restrict__ gt,
    float* __restrict__ Cp)
{
    __shared__ float hrow[QT][CHUNK];   // 8 KB
    const int bid  = blockIdx.x;        // 2048 blocks
    const int b    = bid & 15;
    const int rest = bid >> 4;          // 0..127
    const int qt   = rest & (NQ / QT - 1);  // 0..15
    const int c    = rest >> 4;         // 0..7
    const int q0   = qt * QT;

    const float* hbase = heat + ((size_t)(b * NQ + q0)) * DIM + c * CHUNK;
    #pragma unroll
    for (int i = threadIdx.x; i < QT * CHUNK / 4; i += 256) {
        int r = i >> 7;        // / (CHUNK/4 = 128)
        int k = i & 127;
        ((float4*)hrow[r])[k] = ((const float4*)(hbase + (size_t)r * DIM))[k];
    }
    __syncthreads();

    const int wave = threadIdx.x >> 6;
    const int lane = threadIdx.x & 63;
    const int g0 = wave * 8;
    const float* gbase = gt + ((size_t)(b * NGT + g0)) * DIM + c * CHUNK;

    float acc[8][QT];
    #pragma unroll
    for (int g = 0; g < 8; ++g)
        #pragma unroll
        for (int q = 0; q < QT; ++q) acc[g][q] = 0.f;

    #pragma unroll
    for (int i0 = 0; i0 < CHUNK / 4; i0 += 64) {   // 2 iterations
        const int i = i0 + lane;
        float4 hv[QT];
        #pragma unroll
        for (int q = 0; q < QT; ++q) hv[q] = ((float4*)hrow[q])[i];
        #pragma unroll
        for (int g = 0; g < 8; ++g) {
            float4 gv = ((const float4*)(gbase + (size_t)g * DIM))[i];
            #pragma unroll
            for (int q = 0; q < QT; ++q) {
                acc[g][q] += fabsf(hv[q].x - gv.x) + fabsf(hv[q].y - gv.y) +
                             fabsf(hv[q].z - gv.z) + fabsf(hv[q].w - gv.w);
            }
        }
    }

    // 32-value butterfly across 64 lanes; lane l (l<32) ends with value l
    float r[32];
    #pragma unroll
    for (int k = 0; k < 32; ++k) r[k] = acc[k >> 2][k & 3];
    #pragma unroll
    for (int n = 32, m = 1; n > 1; n >>= 1, m <<= 1) {
        #pragma unroll
        for (int k = 0; k < 32; ++k) {
            if (k < n / 2) {
                float a  = r[2 * k], bb = r[2 * k + 1];
                bool  hi = (lane & m) != 0;
                float keep = hi ? bb : a;
                float send = hi ? a : bb;
                r[k] = keep + __shfl_xor(send, m);
            }
        }
    }
    float tot = r[0] + __shfl_xor(r[0], 32);
    if (lane < 32) {
        int gl = lane >> 2, ql = lane & 3;
        Cp[(((size_t)(b * NQ + (q0 + ql))) * NGT + (g0 + gl)) * NCHUNK + c] = tot;
    }
}

// ---------------------------------------------------------------------------
// Helpers.
// ---------------------------------------------------------------------------
template<int CTRL>
__device__ __forceinline__ float dppmin_t(float x) {
    int t = __builtin_amdgcn_update_dpp(__float_as_int(x), __float_as_int(x),
                                        CTRL, 0xf, 0xf, false);
    return fminf(x, __int_as_float(t));
}
__device__ __forceinline__ float rdlane_f(float x, int l) {
    return __int_as_float(__builtin_amdgcn_readlane(__float_as_int(x), l));
}
// Exact min over all 64 lanes, wave-uniform result.
__device__ __forceinline__ float wavemin64(float x) {
    x = dppmin_t<0xB1>(x);    // quad_perm xor1
    x = dppmin_t<0x4E>(x);    // quad_perm xor2
    x = dppmin_t<0x141>(x);   // row_half_mirror -> min over 8
    x = dppmin_t<0x140>(x);   // row_mirror      -> min over 16
    x = dppmin_t<0x142>(x);   // row_bcast15
    x = dppmin_t<0x143>(x);   // row_bcast31 -> lane63 = min over 64
    return rdlane_f(x, 63);
}

// ---------------------------------------------------------------------------
// Kernel 2: exact rectangular LSAP (Jonker-Volgenant + greedy P1 row init),
// byte-identical to round 10 (best passing, 33.83 us). One block per batch;
// all 4 waves stage cost[g][q] into LDS (conflict-free), wave 0 solves.
// Lane j owns column j (v, shortest, path, SC, row4col); lane i<32 owns row i
// (u, col4row). Argmin = DPP fmin tree + ballot/ffs (first-index tie-break =
// jnp.argmin). All values bit-exact vs the reference trajectory.
// ---------------------------------------------------------------------------
__global__ __launch_bounds__(256, 1) void lsap_kernel(
    const float* __restrict__ Cp, const float* __restrict__ prob,
    const int* __restrict__ label, int* __restrict__ out)
{
    __shared__ float cost[NGT * NQ];
    const int b = blockIdx.x;
    const int tid = threadIdx.x;

    for (int idx = tid; idx < NQ * NGT; idx += 256) {
        int q = idx & 63;
        int g = idx >> 6;
        const float* p = &Cp[(((size_t)(b * NQ + q)) * NGT + g) * NCHUNK];
        float4 v4a = *(const float4*)p;
        float4 v4b = *(const float4*)(p + 4);
        int lb = label[b * NGT + g];
        float cpr = 1.0f - prob[((size_t)(b * NQ + q)) * NCLS + lb];
        float s = ((v4a.x + v4a.y) + (v4a.z + v4a.w)) +
                  ((v4b.x + v4b.y) + (v4b.z + v4b.w));
        cost[g * 64 + q] = s + cpr;
    }
    __syncthreads();
    if (tid >= 64) return;            // wave 0 solves alone
    const int lane = tid;

    const float INF = __builtin_inff();
    float v = 0.f;        // dual for column `lane`
    float u_reg = 0.f;    // dual for row `lane` (valid lane<32)
    int c4r = -1;         // col4row for row `lane` (valid lane<32)
    int r4c = -1;         // row4col for column `lane`

    // ---- P1: greedy row reduction + matching, groups of 8 ----
    #pragma unroll
    for (int gb = 0; gb < NGT; gb += 8) {
        float xs[8]; float ms[8]; int js[8];
        #pragma unroll
        for (int t = 0; t < 8; ++t) xs[t] = cost[((gb + t) << 6) + lane];
        #pragma unroll
        for (int t = 0; t < 8; ++t) {
            ms[t] = wavemin64(xs[t]);
            unsigned long long ball = __ballot(xs[t] == ms[t]);
            js[t] = __ffsll(ball) - 1;
        }
        #pragma unroll
        for (int t = 0; t < 8; ++t) {
            int g = gb + t, j = js[t];
            int rtaken = __builtin_amdgcn_readlane(r4c, j);
            if (rtaken < 0) {
                if (lane == j) r4c = g;
                if (lane == g) c4r = j;
            }
            if (lane == g) u_reg = ms[t];
        }
    }

    // ---- Dijkstra for the unmatched rows ----
    for (int cur = 0; cur < NGT; ++cur) {
        if (__builtin_amdgcn_readlane(c4r, cur) >= 0) continue;  // greedy-matched

        unsigned SRmask = 0;
        float shortest = INF;
        int pathv = 0;
        bool SC = false;
        float minVal = 0.f;
        int i = cur;
        int sink = -1;

        while (sink < 0) {
            SRmask |= (1u << i);
            float ci = cost[(i << 6) + lane];
            float ui = rdlane_f(u_reg, i);
            float lowest = minVal + ci - ui - v;
            if (!SC && lowest < shortest) { shortest = lowest; pathv = i; }
            float masked = SC ? INF : shortest;
            float mv = wavemin64(masked);
            unsigned long long ball = __ballot(masked == mv);
            int j = __ffsll(ball) - 1;          // first-index tie-break
            minVal = mv;
            if (lane == j) SC = true;
            int rr = __builtin_amdgcn_readlane(r4c, j);
            if (rr < 0) sink = j;
            else        i = rr;
        }

        // ---- dual updates (pre-augment col4row) ----
        if (lane == cur) u_reg += minVal;
        {
            float shc = __shfl(shortest, c4r & 63);
            bool rowupd = (lane < NGT) && (lane != cur) && ((SRmask >> lane) & 1u);
            if (rowupd) u_reg += minVal - shc;
        }
        if (SC) v -= minVal - shortest;

        // ---- augment back from sink ----
        int j = sink;
        while (true) {
            int ii = __builtin_amdgcn_readlane(pathv, j);
            if (lane == j) r4c = ii;
            int prev = __builtin_amdgcn_readlane(c4r, ii);
            if (lane == ii) c4r = j;
            if (ii == cur) break;
            j = prev;
        }
    }

    // ---- argsort(col4row) and write (rows, cols) ----
    int cc = c4r;
    int rank = 0;
    for (int t = 0; t < NGT; ++t) {
        int ct = __shfl(c4r, t);
        rank += (ct < cc) ? 1 : 0;
    }
    if (lane < NGT) {
        out[b * NGT + rank] = cc;                   // rows: matched query idx
        out[BS * NGT + b * NGT + rank] = lane;      // cols: corresponding gt idx
    }
}

extern "C" void kernel_launch(void* const* d_in, const int* in_sizes, int n_in,
                              void* d_out, int out_size, void* d_ws, size_t ws_size,
                              hipStream_t stream) {
    const float* prob  = (const float*)d_in[0];
    const int*   label = (const int*)d_in[1];
    const float* heat  = (const float*)d_in[2];
    const float* gt    = (const float*)d_in[3];
    int* out = (int*)d_out;
    float* Cp = (float*)d_ws;   // BS*NQ*NGT*NCHUNK floats = 1 MiB

    cost_kernel<<<dim3(BS * (NQ / QT) * NCHUNK), dim3(256), 0, stream>>>(heat, gt, Cp);
    lsap_kernel<<<dim3(BS), dim3(256), 0, stream>>>(Cp, prob, label, out);
}